// Round 5
// baseline (340.065 us; speedup 1.0000x reference)
//
#include <hip/hip_runtime.h>
#include <math.h>

typedef unsigned short u16;
typedef unsigned int u32;
typedef __bf16 bf16x8 __attribute__((ext_vector_type(8)));
typedef float f32x4 __attribute__((ext_vector_type(4)));

__device__ __forceinline__ float bf2f(u16 v){ union{u32 u;float f;}c; c.u=((u32)v)<<16; return c.f; }
__device__ __forceinline__ u16 f2bf(float f){ union{float f;u32 u;}c; c.f=f; u32 l=(c.u>>16)&1u; c.u+=0x7fffu+l; return (u16)(c.u>>16); }
__device__ __forceinline__ u32 pk2(float a, float b){ return (u32)f2bf(a) | ((u32)f2bf(b)<<16); }
__device__ __forceinline__ uint4 ld8f(const float* p){
  float4 x = ((const float4*)p)[0];
  float4 y = ((const float4*)p)[1];
  uint4 r; r.x=pk2(x.x,x.y); r.y=pk2(x.z,x.w); r.z=pk2(y.x,y.y); r.w=pk2(y.z,y.w);
  return r;
}
__device__ __forceinline__ float fsilu(float x){ return x/(1.f+__expf(-x)); }

// async 16B global -> LDS DMA. Global addr is per-lane; LDS dest is
// wave-uniform base + lane*16 (m104/m108 semantics).
__device__ __forceinline__ void async16(const u16* g, u16* l) {
  __builtin_amdgcn_global_load_lds(
      (const __attribute__((address_space(1))) u32*)(g),
      (__attribute__((address_space(3))) u32*)(l), 16, 0, 0);
}

// ---------------- fused setup kernel ----------------
// sections by blockIdx.x range: [cvt | setup_edges | out_ptr | wbigt | smallw | zero-cnt]
struct SArgs {
  const float *t, *h, *r2, *rbf_e1, *sph_e1, *w1, *w2, *wgw, *wgt, *b2;
  const int *e1_to_e2, *src2;
  u16 *T16, *h16, *rbf2b, *rbf1p, *WbigT, *WcT, *WgtT;
  float *sph_c, *bc2;
  int *out_ptr, *cnt;
  long n_t, n_h, n_r;
  int E1, E2, Nn;
  int B0, B1, B2, B3, B4, B5; // cumulative section ends
};

__global__ __launch_bounds__(256)
void k_setup(SArgs s) {
  int b = blockIdx.x, tid = threadIdx.x;
  if (b < s.B0) {                      // bulk f32->bf16 cvt (t_e2, h, rbf_e2)
    long base = ((long)b*256 + tid)*8;
    if (base < s.n_t) {
      *(uint4*)(s.T16+base) = ld8f(s.t+base);
    } else if (base < s.n_t+s.n_h) {
      long o = base-s.n_t;  *(uint4*)(s.h16+o) = ld8f(s.h+o);
    } else if (base < s.n_t+s.n_h+s.n_r) {
      long o = base-s.n_t-s.n_h; *(uint4*)(s.rbf2b+o) = ld8f(s.r2+o);
    }
  } else if (b < s.B1) {               // scatter rbf_e1, sph_e1[:,1] into e2 order
    int e = (b-s.B0)*256 + tid;
    if (e < s.E1) {
      int f = s.e1_to_e2[e];
      s.sph_c[f] = s.sph_e1[e*3+1];
      const float* src = s.rbf_e1 + (size_t)e*32;
      uint4* d = (uint4*)(s.rbf1p + (size_t)f*32);
      d[0]=ld8f(src); d[1]=ld8f(src+8); d[2]=ld8f(src+16); d[3]=ld8f(src+24);
    }
  } else if (b < s.B2) {               // CSR row pointers
    int n = (b-s.B1)*256 + tid;
    if (n <= s.Nn) {
      int lo=0, hi=s.E2;
      while (lo<hi){ int m=(lo+hi)>>1; if (s.src2[m]<n) lo=m+1; else hi=m; }
      s.out_ptr[n]=lo;
    }
  } else if (b < s.B3) {               // WbigT[n(384)][k(448)]
    int id = (b-s.B2)*256 + tid;
    if (id < 384*448) {
      int n = id/448, k = id%448;
      int q = n>>7, nn = n&127;
      int row = -1;
      if (k<128) row = q*128+k;
      else if (k<256) { if (q==0) row = 384+(k-128); }
      else if (k<384) { if (q==0) row = 512+(k-256); else if (q==1) row = 640+(k-256); }
      else if (k<416) { if (q==0) row = 768+(k-384); else if (q==1) row = 800+(k-384); }
      else { if (q==2) row = 832+(k-416); }
      s.WbigT[id] = (row>=0) ? f2bf(s.w1[row*128+nn]) : (u16)0;
    }
  } else if (b < s.B4) {               // WcT = (w2@wgw)^T, WgtT = wgt^T, bc2 = b2@wgw
    int id = (b-s.B3)*256 + tid;
    if (id < 16384) {
      int n = id&127, k = id>>7;
      float acc = 0.f;
      for (int r=0;r<128;r++) acc += s.w2[k*128+r]*s.wgw[r*128+n];
      s.WcT[n*128+k] = f2bf(acc);
      s.WgtT[n*128+k] = f2bf(s.wgt[k*128+n]);
    } else if (id < 16384+128) {
      int n = id-16384;
      float acc = 0.f;
      for (int r=0;r<128;r++) acc += s.b2[r]*s.wgw[r*128+n];
      s.bc2[n] = acc;
    }
  } else if (b < s.B5) {               // zero cnt
    int e = (b-s.B4)*256 + tid;
    if (e < s.E2) s.cnt[e] = 0;
  }
}

// ---------------- wedge enumeration (thread-parallel) ----------------
__global__ __launch_bounds__(256, 8)
void k_enum(const int* __restrict__ src2, const int* __restrict__ dst2,
            const int* __restrict__ out_ptr, const float* __restrict__ sph_c,
            int4* __restrict__ wrec, int* __restrict__ cnt, int E2) {
  int id = blockIdx.x*256 + threadIdx.x;
  if (id >= E2*8) return;
  int gw = id >> 3, d = id & 7;
  int i = src2[gw], j = dst2[gw];
  int f = out_ptr[i] + d;
  if (f >= out_ptr[i+1]) return;
  int k = dst2[f];
  int lo = out_ptr[k], hi = out_ptr[k+1], hi0 = hi;
  while (lo<hi) { int m=(lo+hi)>>1; if (dst2[m]<j) lo=m+1; else hi=m; }
  if (lo < hi0 && dst2[lo]==j) {
    float cf = sph_c[f]*sph_c[lo];
    int slot = atomicAdd(&cnt[gw], 1);
    int4 r; r.x=f; r.y=lo; r.z=__float_as_int(cf); r.w=0;
    wrec[(size_t)gw*8 + slot] = r;
  }
}

// ---------------- wedge accumulation ----------------
__global__ __launch_bounds__(256, 8)
void k_wedge2(const u16* __restrict__ Q1, const u16* __restrict__ Q2,
              const u16* __restrict__ P3, const int4* __restrict__ wrec,
              const int* __restrict__ cnt, const float* __restrict__ w1,
              u16* __restrict__ S, int E2) {
  int gw = (int)((blockIdx.x*256 + threadIdx.x) >> 6);
  int lane = threadIdx.x & 63;
  if (gw >= E2) return;
  u32 p3u = ((const u32*)(P3 + (size_t)gw*128))[lane];
  float p30 = bf2f((u16)(p3u&0xffff)), p31 = bf2f((u16)(p3u>>16));
  float2 wv = ((const float2*)(w1 + 864*128))[lane];
  const u32* q1b = (const u32*)Q1;
  const u32* q2b = (const u32*)Q2;
  const int4* wr = wrec + (size_t)gw*8;
  int c = cnt[gw];
  float a0=0.f, a1=0.f;
  int w = 0;
  for (; w+2<=c; w+=2) {
    int4 rA = wr[w], rB = wr[w+1];
    u32 xA = q1b[(size_t)rA.x*64 + lane];
    u32 yA = q2b[(size_t)rA.y*64 + lane];
    u32 xB = q1b[(size_t)rB.x*64 + lane];
    u32 yB = q2b[(size_t)rB.y*64 + lane];
    float cfA = __int_as_float(rA.z), cfB = __int_as_float(rB.z);
    float x0 = p30 + bf2f((u16)(xA&0xffff)) + bf2f((u16)(yA&0xffff)) + cfA*wv.x;
    float x1 = p31 + bf2f((u16)(xA>>16))    + bf2f((u16)(yA>>16))    + cfA*wv.y;
    float z0 = p30 + bf2f((u16)(xB&0xffff)) + bf2f((u16)(yB&0xffff)) + cfB*wv.x;
    float z1 = p31 + bf2f((u16)(xB>>16))    + bf2f((u16)(yB>>16))    + cfB*wv.y;
    a0 += fsilu(x0) + fsilu(z0);
    a1 += fsilu(x1) + fsilu(z1);
  }
  if (w < c) {
    int4 rA = wr[w];
    u32 xA = q1b[(size_t)rA.x*64 + lane];
    u32 yA = q2b[(size_t)rA.y*64 + lane];
    float cfA = __int_as_float(rA.z);
    float x0 = p30 + bf2f((u16)(xA&0xffff)) + bf2f((u16)(yA&0xffff)) + cfA*wv.x;
    float x1 = p31 + bf2f((u16)(xA>>16))    + bf2f((u16)(yA>>16))    + cfA*wv.y;
    a0 += fsilu(x0);
    a1 += fsilu(x1);
  }
  ((u32*)(S + (size_t)gw*128))[lane] = pk2(a0, a1);
}

// ---------------- MFMA GEMM with global_load_lds DMA pipeline ----------------
// LDS layout per 32-k chunk (8KB): plane q (k-sub of 8 elems) * 2048B + row*16B.
// DMA chunk c (=issue*4+wave, 1KB): q=c>>1, rows (c&1)*64 + lane.
// MODE 0: K=448 gathered A -> Q1/Q2/P3 (blockIdx.y = bn; +b1 for bn==2)
// MODE 1: fused pair of K=128 GEMMs: acc0 = S@WcT, acc1 = T16@WgtT,
//         epilogue: out = t + sigmoid(acc0+cnt*bc2+bgw)*tanh(acc1+bgt)  (f32)
struct GArgs {
  const u16 *T16, *h16, *rbf1p, *rbf2b, *Asrc;
  const int *src2, *dst2, *cnt;
  const u16 *Bmat, *Bmat2;
  const float *b1, *bgw, *bgt, *bc2;
  u16 *out0, *out1, *out2;
  float* outf;
  int M;
};

template<int MODE>
__global__ __launch_bounds__(256, 2)
void k_gemm(GArgs a) {
  constexpr int NK = (MODE==0)?14:8;
  constexpr int NA = (MODE==0)?1:2;
  __shared__ u16 As[2][4096];
  __shared__ u16 Bs[2][4096];
  const int tid = threadIdx.x;
  const int bm = blockIdx.x, bn = (MODE==0)? blockIdx.y : 0;
  const int lane = tid & 63, wave = tid >> 6;
  const int wm = wave >> 1, wn = wave & 1;
  const int quad = lane >> 4, l16 = lane & 15;

  // DMA row for this thread (A row index within tile; also B row = out col)
  const int ar = (wave & 1)*64 + lane;
  const int qh = wave >> 1;
  long fa = (long)bm*128 + ar;
  if (fa >= a.M) fa = a.M-1;

  const u16 *tb, *hs, *hd, *r1, *r2;
  if constexpr (MODE==0) {
    int sa = a.src2[fa], da = a.dst2[fa];
    tb = a.T16 + fa*128; hs = a.h16 + (long)sa*128; hd = a.h16 + (long)da*128;
    r1 = a.rbf1p + fa*32; r2 = a.rbf2b + fa*32;
  } else {
    tb = a.Asrc + fa*128;    // S
    hs = a.T16 + fa*128;     // t_e2 (bf16)
  }
  auto agp = [&](int ks, int q) -> const u16* {
    if constexpr (MODE==0) {
      if (ks<4)   return tb + ks*32 + q*8;
      if (ks<8)   return hs + (ks-4)*32 + q*8;
      if (ks<12)  return hd + (ks-8)*32 + q*8;
      if (ks==12) return r1 + q*8;
      return r2 + q*8;
    } else {
      if (ks<4) return tb + ks*32 + q*8;
      return hs + (ks-4)*32 + q*8;
    }
  };
  const u16* Bb0; const u16* Bb1 = nullptr;
  if constexpr (MODE==0) { Bb0 = a.Bmat + (long)(bn*128 + ar)*448; }
  else { Bb0 = a.Bmat + (long)ar*128; Bb1 = a.Bmat2 + (long)ar*128; }
  auto bgp = [&](int ks, int q) -> const u16* {
    if constexpr (MODE==0) return Bb0 + ks*32 + q*8;
    else return (ks<4) ? (Bb0 + ks*32 + q*8) : (Bb1 + (ks-4)*32 + q*8);
  };
  auto issue = [&](int ks, int buf) {
    async16(agp(ks, qh),   As[buf] + wave*512);
    async16(agp(ks, qh+2), As[buf] + (4+wave)*512);
    async16(bgp(ks, qh),   Bs[buf] + wave*512);
    async16(bgp(ks, qh+2), Bs[buf] + (4+wave)*512);
  };

  issue(0, 0);
  __syncthreads();

  f32x4 acc[NA][4][4] = {};
  for (int ks=0; ks<NK; ks++) {
    const int buf = ks & 1;
    if (ks+1 < NK) issue(ks+1, buf^1);
    const int sel = (NA==2) ? (ks>>2) : 0;
    bf16x8 af[4], bfr[4];
    #pragma unroll
    for (int t=0;t<4;t++) {
      af[t]  = *(const bf16x8*)(As[buf] + quad*1024 + (wm*64 + t*16 + l16)*8);
      bfr[t] = *(const bf16x8*)(Bs[buf] + quad*1024 + (wn*64 + t*16 + l16)*8);
    }
    #pragma unroll
    for (int tm=0;tm<4;tm++)
      #pragma unroll
      for (int tn=0;tn<4;tn++)
        acc[sel][tm][tn] = __builtin_amdgcn_mfma_f32_16x16x32_bf16(af[tm], bfr[tn], acc[sel][tm][tn], 0,0,0);
    __syncthreads();   // drains this iter's DMA (vmcnt) + protects buffer reuse
  }

  // epilogue (C/D: col=lane&15, row=quad*4+reg)
  #pragma unroll
  for (int tm=0;tm<4;tm++) {
    const int rloc = wm*64 + tm*16 + quad*4;
    #pragma unroll
    for (int r=0;r<4;r++) {
      long row = (long)bm*128 + rloc + r;
      if (row >= a.M) continue;
      #pragma unroll
      for (int tn=0;tn<4;tn++) {
        const int col = wn*64 + tn*16 + l16;
        if constexpr (MODE==0) {
          float v = acc[0][tm][tn][r];
          u16* dst = (bn==0)? a.out0 : (bn==1)? a.out1 : a.out2;
          if (bn==2) v += a.b1[col];
          dst[row*128 + col] = f2bf(v);
        } else {
          float u = acc[0][tm][tn][r] + (float)a.cnt[row]*a.bc2[col] + a.bgw[col];
          float g = 1.f/(1.f+__expf(-u));
          float vv = acc[1][tm][tn][r] + a.bgt[col];
          float th = 1.f - 2.f/(__expf(2.f*vv)+1.f);
          float t  = bf2f(a.T16[row*128+col]);
          a.outf[row*128+col] = t + g*th;
        }
      }
    }
  }
}

// ---------------- launch ----------------
extern "C" void kernel_launch(void* const* d_in, const int* in_sizes, int n_in,
                              void* d_out, int out_size, void* d_ws, size_t ws_size,
                              hipStream_t stream) {
  const float* t_e2  = (const float*)d_in[0];
  const float* h     = (const float*)d_in[1];
  const int* ei2     = (const int*)d_in[3];
  const int* e1_to_e2 = (const int*)d_in[4];
  const float* rbf_e1 = (const float*)d_in[7];
  const float* rbf_e2 = (const float*)d_in[8];
  const float* sph_e1 = (const float*)d_in[9];
  const float* w1  = (const float*)d_in[11];
  const float* b1  = (const float*)d_in[12];
  const float* w2  = (const float*)d_in[13];
  const float* b2  = (const float*)d_in[14];
  const float* wgw = (const float*)d_in[15];
  const float* bgw = (const float*)d_in[16];
  const float* wgt = (const float*)d_in[17];
  const float* bgt = (const float*)d_in[18];

  const int E2 = in_sizes[0]/128;
  const int Nn = in_sizes[1]/128;
  const int E1 = in_sizes[5];
  const int* src2 = ei2;
  const int* dst2 = ei2 + E2;

  // workspace carve (16B-aligned regions)
  char* p = (char*)d_ws;
  u16* Q1 = (u16*)p;       p += (size_t)E2*128*2;
  u16* Q2 = (u16*)p;       p += (size_t)E2*128*2;
  u16* P3 = (u16*)p;       p += (size_t)E2*128*2;   // aliased as S after wedge
  u16* T16 = (u16*)p;      p += (size_t)E2*128*2;
  u16* h16 = (u16*)p;      p += (size_t)Nn*128*2;
  u16* rbf2b = (u16*)p;    p += (size_t)E2*32*2;
  u16* rbf1p = (u16*)p;    p += (size_t)E2*32*2;
  u16* WbigT = (u16*)p;    p += (size_t)384*448*2;
  u16* WcT   = (u16*)p;    p += (size_t)128*128*2;
  u16* WgtT  = (u16*)p;    p += (size_t)128*128*2;
  float* sph_c = (float*)p; p += (size_t)E2*4;
  float* bc2   = (float*)p; p += 512;
  int* out_ptr = (int*)p;   p += (((size_t)(Nn+1)*4 + 63)/64)*64;
  int* cnt     = (int*)p;   p += (size_t)E2*4;
  int4* wrec   = (int4*)p;  p += (size_t)E2*8*16;
  u16* S = P3;   // alias: safe (row-local read-then-write in k_wedge2)

  long n_t = (long)E2*128, n_h = (long)Nn*128, n_r = (long)E2*32;
  long tot8 = (n_t+n_h+n_r)/8;

  SArgs s;
  s.t=t_e2; s.h=h; s.r2=rbf_e2; s.rbf_e1=rbf_e1; s.sph_e1=sph_e1;
  s.w1=w1; s.w2=w2; s.wgw=wgw; s.wgt=wgt; s.b2=b2;
  s.e1_to_e2=e1_to_e2; s.src2=src2;
  s.T16=T16; s.h16=h16; s.rbf2b=rbf2b; s.rbf1p=rbf1p;
  s.WbigT=WbigT; s.WcT=WcT; s.WgtT=WgtT;
  s.sph_c=sph_c; s.bc2=bc2; s.out_ptr=out_ptr; s.cnt=cnt;
  s.n_t=n_t; s.n_h=n_h; s.n_r=n_r; s.E1=E1; s.E2=E2; s.Nn=Nn;
  int B0 = (int)((tot8+255)/256);
  int B1 = B0 + (E1+255)/256;
  int B2 = B1 + (Nn+1+255)/256;
  int B3 = B2 + (384*448+255)/256;
  int B4 = B3 + (16512+255)/256;
  int B5 = B4 + (E2+255)/256;
  s.B0=B0; s.B1=B1; s.B2=B2; s.B3=B3; s.B4=B4; s.B5=B5;
  k_setup<<<B5, 256, 0, stream>>>(s);

  k_enum<<<(E2*8+255)/256, 256, 0, stream>>>(src2, dst2, out_ptr, sph_c, wrec, cnt, E2);

  const int Mb = (E2+127)/128;
  {
    GArgs a = {};
    a.T16=T16; a.h16=h16; a.rbf1p=rbf1p; a.rbf2b=rbf2b;
    a.src2=src2; a.dst2=dst2; a.Bmat=WbigT; a.b1=b1;
    a.out0=Q1; a.out1=Q2; a.out2=P3; a.M=E2;
    k_gemm<0><<<dim3(Mb,3), 256, 0, stream>>>(a);
  }
  k_wedge2<<<(E2+3)/4, 256, 0, stream>>>(Q1, Q2, P3, wrec, cnt, w1, S, E2);
  {
    GArgs a = {};
    a.Asrc=S; a.T16=T16; a.cnt=cnt; a.Bmat=WcT; a.Bmat2=WgtT;
    a.bgw=bgw; a.bgt=bgt; a.bc2=bc2;
    a.outf=(float*)d_out; a.M=E2;
    k_gemm<1><<<dim3(Mb,1), 256, 0, stream>>>(a);
  }
}

// Round 6
// 336.855 us; speedup vs baseline: 1.0095x; 1.0095x over previous
//
#include <hip/hip_runtime.h>
#include <math.h>

typedef unsigned short u16;
typedef unsigned int u32;
typedef __bf16 bf16x8 __attribute__((ext_vector_type(8)));
typedef float f32x4 __attribute__((ext_vector_type(4)));

__device__ __forceinline__ float bf2f(u16 v){ union{u32 u;float f;}c; c.u=((u32)v)<<16; return c.f; }
__device__ __forceinline__ u16 f2bf(float f){ union{float f;u32 u;}c; c.f=f; u32 l=(c.u>>16)&1u; c.u+=0x7fffu+l; return (u16)(c.u>>16); }
__device__ __forceinline__ u32 pk2(float a, float b){ return (u32)f2bf(a) | ((u32)f2bf(b)<<16); }
__device__ __forceinline__ uint4 ld8f(const float* p){
  float4 x = ((const float4*)p)[0];
  float4 y = ((const float4*)p)[1];
  uint4 r; r.x=pk2(x.x,x.y); r.y=pk2(x.z,x.w); r.z=pk2(y.x,y.y); r.w=pk2(y.z,y.w);
  return r;
}
__device__ __forceinline__ float fsilu(float x){ return x/(1.f+__expf(-x)); }

// async 16B global -> LDS DMA (per-lane global addr, wave-uniform LDS base + lane*16)
__device__ __forceinline__ void async16(const u16* g, u16* l) {
  __builtin_amdgcn_global_load_lds(
      (const __attribute__((address_space(1))) u32*)(g),
      (__attribute__((address_space(3))) u32*)(l), 16, 0, 0);
}

// ---------------- fused setup kernel ----------------
struct SArgs {
  const float *t, *h, *r2, *rbf_e1, *sph_e1, *w1, *w2, *wgw, *wgt, *b2;
  const int *e1_to_e2, *src2;
  u16 *T16, *h16, *rbf2b, *rbf1p, *WbigT, *WcT, *WgtT;
  float *sph_c, *bc2;
  int *out_ptr, *cnt;
  long n_t, n_h, n_r;
  int E1, E2, Nn;
  int B0, B1, B2, B3, B4, B5;
};

__global__ __launch_bounds__(256)
void k_setup(SArgs s) {
  int b = blockIdx.x, tid = threadIdx.x;
  if (b < s.B0) {                      // bulk f32->bf16 cvt (t_e2, h, rbf_e2)
    long base = ((long)b*256 + tid)*8;
    if (base < s.n_t) {
      *(uint4*)(s.T16+base) = ld8f(s.t+base);
    } else if (base < s.n_t+s.n_h) {
      long o = base-s.n_t;  *(uint4*)(s.h16+o) = ld8f(s.h+o);
    } else if (base < s.n_t+s.n_h+s.n_r) {
      long o = base-s.n_t-s.n_h; *(uint4*)(s.rbf2b+o) = ld8f(s.r2+o);
    }
  } else if (b < s.B1) {               // scatter rbf_e1, sph_e1[:,1] into e2 order
    int e = (b-s.B0)*256 + tid;
    if (e < s.E1) {
      int f = s.e1_to_e2[e];
      s.sph_c[f] = s.sph_e1[e*3+1];
      const float* src = s.rbf_e1 + (size_t)e*32;
      uint4* d = (uint4*)(s.rbf1p + (size_t)f*32);
      d[0]=ld8f(src); d[1]=ld8f(src+8); d[2]=ld8f(src+16); d[3]=ld8f(src+24);
    }
  } else if (b < s.B2) {               // CSR row pointers
    int n = (b-s.B1)*256 + tid;
    if (n <= s.Nn) {
      int lo=0, hi=s.E2;
      while (lo<hi){ int m=(lo+hi)>>1; if (s.src2[m]<n) lo=m+1; else hi=m; }
      s.out_ptr[n]=lo;
    }
  } else if (b < s.B3) {               // WbigT[n(384)][k(448)]
    int id = (b-s.B2)*256 + tid;
    if (id < 384*448) {
      int n = id/448, k = id%448;
      int q = n>>7, nn = n&127;
      int row = -1;
      if (k<128) row = q*128+k;
      else if (k<256) { if (q==0) row = 384+(k-128); }
      else if (k<384) { if (q==0) row = 512+(k-256); else if (q==1) row = 640+(k-256); }
      else if (k<416) { if (q==0) row = 768+(k-384); else if (q==1) row = 800+(k-384); }
      else { if (q==2) row = 832+(k-416); }
      s.WbigT[id] = (row>=0) ? f2bf(s.w1[row*128+nn]) : (u16)0;
    }
  } else if (b < s.B4) {               // WcT = (w2@wgw)^T, WgtT = wgt^T, bc2 = b2@wgw
    int id = (b-s.B3)*256 + tid;
    if (id < 16384) {
      int n = id&127, k = id>>7;
      float acc = 0.f;
      for (int r=0;r<128;r++) acc += s.w2[k*128+r]*s.wgw[r*128+n];
      s.WcT[n*128+k] = f2bf(acc);
      s.WgtT[n*128+k] = f2bf(s.wgt[k*128+n]);
    } else if (id < 16384+128) {
      int n = id-16384;
      float acc = 0.f;
      for (int r=0;r<128;r++) acc += s.b2[r]*s.wgw[r*128+n];
      s.bc2[n] = acc;
    }
  } else if (b < s.B5) {               // zero cnt
    int e = (b-s.B4)*256 + tid;
    if (e < s.E2) s.cnt[e] = 0;
  }
}

// ---------------- wedge enumeration (thread-parallel) ----------------
__global__ __launch_bounds__(256, 8)
void k_enum(const int* __restrict__ src2, const int* __restrict__ dst2,
            const int* __restrict__ out_ptr, const float* __restrict__ sph_c,
            int4* __restrict__ wrec, int* __restrict__ cnt, int E2) {
  int id = blockIdx.x*256 + threadIdx.x;
  if (id >= E2*8) return;
  int gw = id >> 3, d = id & 7;
  int i = src2[gw], j = dst2[gw];
  int f = out_ptr[i] + d;
  if (f >= out_ptr[i+1]) return;
  int k = dst2[f];
  int lo = out_ptr[k], hi = out_ptr[k+1], hi0 = hi;
  while (lo<hi) { int m=(lo+hi)>>1; if (dst2[m]<j) lo=m+1; else hi=m; }
  if (lo < hi0 && dst2[lo]==j) {
    float cf = sph_c[f]*sph_c[lo];
    int slot = atomicAdd(&cnt[gw], 1);
    int4 r; r.x=f; r.y=lo; r.z=__float_as_int(cf); r.w=0;
    wrec[(size_t)gw*8 + slot] = r;
  }
}

// ---------------- wedge accumulation ----------------
__global__ __launch_bounds__(256, 8)
void k_wedge2(const u16* __restrict__ Q1, const u16* __restrict__ Q2,
              const u16* __restrict__ P3, const int4* __restrict__ wrec,
              const int* __restrict__ cnt, const float* __restrict__ w1,
              u16* __restrict__ S, int E2) {
  int gw = (int)((blockIdx.x*256 + threadIdx.x) >> 6);
  int lane = threadIdx.x & 63;
  if (gw >= E2) return;
  u32 p3u = ((const u32*)(P3 + (size_t)gw*128))[lane];
  float p30 = bf2f((u16)(p3u&0xffff)), p31 = bf2f((u16)(p3u>>16));
  float2 wv = ((const float2*)(w1 + 864*128))[lane];
  const u32* q1b = (const u32*)Q1;
  const u32* q2b = (const u32*)Q2;
  const int4* wr = wrec + (size_t)gw*8;
  int c = cnt[gw];
  float a0=0.f, a1=0.f;
  int w = 0;
  for (; w+2<=c; w+=2) {
    int4 rA = wr[w], rB = wr[w+1];
    u32 xA = q1b[(size_t)rA.x*64 + lane];
    u32 yA = q2b[(size_t)rA.y*64 + lane];
    u32 xB = q1b[(size_t)rB.x*64 + lane];
    u32 yB = q2b[(size_t)rB.y*64 + lane];
    float cfA = __int_as_float(rA.z), cfB = __int_as_float(rB.z);
    float x0 = p30 + bf2f((u16)(xA&0xffff)) + bf2f((u16)(yA&0xffff)) + cfA*wv.x;
    float x1 = p31 + bf2f((u16)(xA>>16))    + bf2f((u16)(yA>>16))    + cfA*wv.y;
    float z0 = p30 + bf2f((u16)(xB&0xffff)) + bf2f((u16)(yB&0xffff)) + cfB*wv.x;
    float z1 = p31 + bf2f((u16)(xB>>16))    + bf2f((u16)(yB>>16))    + cfB*wv.y;
    a0 += fsilu(x0) + fsilu(z0);
    a1 += fsilu(x1) + fsilu(z1);
  }
  if (w < c) {
    int4 rA = wr[w];
    u32 xA = q1b[(size_t)rA.x*64 + lane];
    u32 yA = q2b[(size_t)rA.y*64 + lane];
    float cfA = __int_as_float(rA.z);
    float x0 = p30 + bf2f((u16)(xA&0xffff)) + bf2f((u16)(yA&0xffff)) + cfA*wv.x;
    float x1 = p31 + bf2f((u16)(xA>>16))    + bf2f((u16)(yA>>16))    + cfA*wv.y;
    a0 += fsilu(x0);
    a1 += fsilu(x1);
  }
  ((u32*)(S + (size_t)gw*128))[lane] = pk2(a0, a1);
}

// ---------------- gemm0: K=448 gathered, global_load_lds DMA pipeline ----------------
struct GArgs {
  const u16 *T16, *h16, *rbf1p, *rbf2b;
  const int *src2, *dst2;
  const u16 *Bmat;
  const float *b1;
  u16 *out0, *out1, *out2;
  int M;
};

__global__ __launch_bounds__(256, 2)
void k_gemm0(GArgs a) {
  constexpr int NK = 14;
  __shared__ u16 As[2][4096];
  __shared__ u16 Bs[2][4096];
  const int tid = threadIdx.x;
  const int bm = blockIdx.x, bn = blockIdx.y;
  const int lane = tid & 63, wave = tid >> 6;
  const int wm = wave >> 1, wn = wave & 1;
  const int quad = lane >> 4, l16 = lane & 15;

  const int ar = (wave & 1)*64 + lane;
  const int qh = wave >> 1;
  long fa = (long)bm*128 + ar;
  if (fa >= a.M) fa = a.M-1;

  int sa = a.src2[fa], da = a.dst2[fa];
  const u16* tb = a.T16 + fa*128;
  const u16* hs = a.h16 + (long)sa*128;
  const u16* hd = a.h16 + (long)da*128;
  const u16* r1 = a.rbf1p + fa*32;
  const u16* r2 = a.rbf2b + fa*32;
  auto agp = [&](int ks, int q) -> const u16* {
    if (ks<4)   return tb + ks*32 + q*8;
    if (ks<8)   return hs + (ks-4)*32 + q*8;
    if (ks<12)  return hd + (ks-8)*32 + q*8;
    if (ks==12) return r1 + q*8;
    return r2 + q*8;
  };
  const u16* Bb0 = a.Bmat + (long)(bn*128 + ar)*448;
  auto issue = [&](int ks, int buf) {
    async16(agp(ks, qh),        As[buf] + wave*512);
    async16(agp(ks, qh+2),      As[buf] + (4+wave)*512);
    async16(Bb0 + ks*32 + qh*8,     Bs[buf] + wave*512);
    async16(Bb0 + ks*32 + (qh+2)*8, Bs[buf] + (4+wave)*512);
  };

  issue(0, 0);
  __syncthreads();

  f32x4 acc[4][4] = {};
  for (int ks=0; ks<NK; ks++) {
    const int buf = ks & 1;
    if (ks+1 < NK) issue(ks+1, buf^1);
    bf16x8 af[4], bfr[4];
    #pragma unroll
    for (int t=0;t<4;t++) {
      af[t]  = *(const bf16x8*)(As[buf] + quad*1024 + (wm*64 + t*16 + l16)*8);
      bfr[t] = *(const bf16x8*)(Bs[buf] + quad*1024 + (wn*64 + t*16 + l16)*8);
    }
    #pragma unroll
    for (int tm=0;tm<4;tm++)
      #pragma unroll
      for (int tn=0;tn<4;tn++)
        acc[tm][tn] = __builtin_amdgcn_mfma_f32_16x16x32_bf16(af[tm], bfr[tn], acc[tm][tn], 0,0,0);
    __syncthreads();
  }

  #pragma unroll
  for (int tm=0;tm<4;tm++) {
    const int rloc = wm*64 + tm*16 + quad*4;
    #pragma unroll
    for (int r=0;r<4;r++) {
      long row = (long)bm*128 + rloc + r;
      if (row >= a.M) continue;
      #pragma unroll
      for (int tn=0;tn<4;tn++) {
        const int col = wn*64 + tn*16 + l16;
        float v = acc[tm][tn][r];
        u16* dst = (bn==0)? a.out0 : (bn==1)? a.out1 : a.out2;
        if (bn==2) v += a.b1[col];
        dst[row*128 + col] = f2bf(v);
      }
    }
  }
}

// ---------------- fused tail GEMM: no LDS, no barriers ----------------
// block = 64 rows; wave w computes rows[0..63] x cols[w*32 .. w*32+31].
// acc0 = S@WcT (sigmoid branch), acc1 = T16@WgtT (tanh branch).
// out = t + sigmoid(acc0 + cnt*bc2 + bgw) * tanh(acc1 + bgt)
__global__ __launch_bounds__(256, 4)
void k_tail(const u16* __restrict__ S, const u16* __restrict__ T16,
            const u16* __restrict__ WcT, const u16* __restrict__ WgtT,
            const int* __restrict__ cnt, const float* __restrict__ bc2,
            const float* __restrict__ bgw, const float* __restrict__ bgt,
            float* __restrict__ outf, int M) {
  const int tid = threadIdx.x;
  const int lane = tid & 63, wave = tid >> 6;
  const int quad = lane >> 4, l16 = lane & 15;
  const long r0 = (long)blockIdx.x*64;

  f32x4 acc[2][4][2] = {};
  #pragma unroll
  for (int ks=0; ks<8; ks++) {
    const int sel = ks>>2, kb = (ks&3)*32;
    const u16* Ab = sel ? T16 : S;
    const u16* Bb = sel ? WgtT : WcT;
    bf16x8 av[4], bv[2];
    #pragma unroll
    for (int tm=0;tm<4;tm++) {
      long row = r0 + tm*16 + l16; if (row >= M) row = M-1;
      av[tm] = *(const bf16x8*)(Ab + row*128 + kb + quad*8);
    }
    #pragma unroll
    for (int tn=0;tn<2;tn++) {
      int col = wave*32 + tn*16 + l16;
      bv[tn] = *(const bf16x8*)(Bb + (long)col*128 + kb + quad*8);
    }
    #pragma unroll
    for (int tm=0;tm<4;tm++)
      #pragma unroll
      for (int tn=0;tn<2;tn++)
        acc[sel][tm][tn] = __builtin_amdgcn_mfma_f32_16x16x32_bf16(av[tm], bv[tn], acc[sel][tm][tn], 0,0,0);
  }

  #pragma unroll
  for (int tm=0;tm<4;tm++) {
    #pragma unroll
    for (int r=0;r<4;r++) {
      long row = r0 + tm*16 + quad*4 + r;
      if (row >= M) continue;
      float cn = (float)cnt[row];
      #pragma unroll
      for (int tn=0;tn<2;tn++) {
        int col = wave*32 + tn*16 + l16;
        float u = acc[0][tm][tn][r] + cn*bc2[col] + bgw[col];
        float g = 1.f/(1.f+__expf(-u));
        float vv = acc[1][tm][tn][r] + bgt[col];
        float th = 1.f - 2.f/(__expf(2.f*vv)+1.f);
        float t = bf2f(T16[row*128+col]);
        outf[row*128+col] = t + g*th;
      }
    }
  }
}

// ---------------- launch ----------------
extern "C" void kernel_launch(void* const* d_in, const int* in_sizes, int n_in,
                              void* d_out, int out_size, void* d_ws, size_t ws_size,
                              hipStream_t stream) {
  const float* t_e2  = (const float*)d_in[0];
  const float* h     = (const float*)d_in[1];
  const int* ei2     = (const int*)d_in[3];
  const int* e1_to_e2 = (const int*)d_in[4];
  const float* rbf_e1 = (const float*)d_in[7];
  const float* rbf_e2 = (const float*)d_in[8];
  const float* sph_e1 = (const float*)d_in[9];
  const float* w1  = (const float*)d_in[11];
  const float* b1  = (const float*)d_in[12];
  const float* w2  = (const float*)d_in[13];
  const float* b2  = (const float*)d_in[14];
  const float* wgw = (const float*)d_in[15];
  const float* bgw = (const float*)d_in[16];
  const float* wgt = (const float*)d_in[17];
  const float* bgt = (const float*)d_in[18];

  const int E2 = in_sizes[0]/128;
  const int Nn = in_sizes[1]/128;
  const int E1 = in_sizes[5];
  const int* src2 = ei2;
  const int* dst2 = ei2 + E2;

  char* p = (char*)d_ws;
  u16* Q1 = (u16*)p;       p += (size_t)E2*128*2;
  u16* Q2 = (u16*)p;       p += (size_t)E2*128*2;
  u16* P3 = (u16*)p;       p += (size_t)E2*128*2;   // aliased as S after wedge
  u16* T16 = (u16*)p;      p += (size_t)E2*128*2;
  u16* h16 = (u16*)p;      p += (size_t)Nn*128*2;
  u16* rbf2b = (u16*)p;    p += (size_t)E2*32*2;
  u16* rbf1p = (u16*)p;    p += (size_t)E2*32*2;
  u16* WbigT = (u16*)p;    p += (size_t)384*448*2;
  u16* WcT   = (u16*)p;    p += (size_t)128*128*2;
  u16* WgtT  = (u16*)p;    p += (size_t)128*128*2;
  float* sph_c = (float*)p; p += (size_t)E2*4;
  float* bc2   = (float*)p; p += 512;
  int* out_ptr = (int*)p;   p += (((size_t)(Nn+1)*4 + 63)/64)*64;
  int* cnt     = (int*)p;   p += (size_t)E2*4;
  int4* wrec   = (int4*)p;  p += (size_t)E2*8*16;
  u16* S = P3;   // alias: safe (row-local read-then-write in k_wedge2)

  long n_t = (long)E2*128, n_h = (long)Nn*128, n_r = (long)E2*32;
  long tot8 = (n_t+n_h+n_r)/8;

  SArgs s;
  s.t=t_e2; s.h=h; s.r2=rbf_e2; s.rbf_e1=rbf_e1; s.sph_e1=sph_e1;
  s.w1=w1; s.w2=w2; s.wgw=wgw; s.wgt=wgt; s.b2=b2;
  s.e1_to_e2=e1_to_e2; s.src2=src2;
  s.T16=T16; s.h16=h16; s.rbf2b=rbf2b; s.rbf1p=rbf1p;
  s.WbigT=WbigT; s.WcT=WcT; s.WgtT=WgtT;
  s.sph_c=sph_c; s.bc2=bc2; s.out_ptr=out_ptr; s.cnt=cnt;
  s.n_t=n_t; s.n_h=n_h; s.n_r=n_r; s.E1=E1; s.E2=E2; s.Nn=Nn;
  int B0 = (int)((tot8+255)/256);
  int B1 = B0 + (E1+255)/256;
  int B2 = B1 + (Nn+1+255)/256;
  int B3 = B2 + (384*448+255)/256;
  int B4 = B3 + (16512+255)/256;
  int B5 = B4 + (E2+255)/256;
  s.B0=B0; s.B1=B1; s.B2=B2; s.B3=B3; s.B4=B4; s.B5=B5;
  k_setup<<<B5, 256, 0, stream>>>(s);

  k_enum<<<(E2*8+255)/256, 256, 0, stream>>>(src2, dst2, out_ptr, sph_c, wrec, cnt, E2);

  const int Mb = (E2+127)/128;
  {
    GArgs a = {};
    a.T16=T16; a.h16=h16; a.rbf1p=rbf1p; a.rbf2b=rbf2b;
    a.src2=src2; a.dst2=dst2; a.Bmat=WbigT; a.b1=b1;
    a.out0=Q1; a.out1=Q2; a.out2=P3; a.M=E2;
    k_gemm0<<<dim3(Mb,3), 256, 0, stream>>>(a);
  }
  k_wedge2<<<(E2+3)/4, 256, 0, stream>>>(Q1, Q2, P3, wrec, cnt, w1, S, E2);

  const int Mb64 = (E2+63)/64;
  k_tail<<<Mb64, 256, 0, stream>>>(S, T16, WcT, WgtT, cnt, bc2, bgw, bgt,
                                   (float*)d_out, E2);
}